// Round 1
// 1222.142 us; speedup vs baseline: 1.2788x; 1.2788x over previous
//
#include <hip/hip_runtime.h>
#include <cstddef>

#define DEVINL __device__ __forceinline__

typedef __attribute__((ext_vector_type(8))) short bf16x8;
typedef __attribute__((ext_vector_type(4))) float f32x4;

DEVINL unsigned short f2bf(float f) {
  unsigned int u = __builtin_bit_cast(unsigned int, f);
  u += 0x7FFFu + ((u >> 16) & 1u);
  return (unsigned short)(u >> 16);
}

DEVINL float sigm(float x) { return 1.0f / (1.0f + __expf(-x)); }

// ---------------------------------------------------------------------------
// Node GEMMs: A = nf@Wg1^T, Bm = nf@Wg2^T, S = nf@Ws^T + bs, D = nf@Wd^T + bd
// (bg cancels under BN mean subtraction)
// ---------------------------------------------------------------------------
__global__ __launch_bounds__(256) void node_gemm_k(
    const float* __restrict__ nf, const float* __restrict__ Wg,
    const float* __restrict__ Ws, const float* __restrict__ bs,
    const float* __restrict__ Wd, const float* __restrict__ bd,
    float* __restrict__ A, float* __restrict__ Bm,
    float* __restrict__ S, float* __restrict__ D, int N) {
  __shared__ float sNf[32 * 128];
  const int n0 = blockIdx.x * 32;
  for (int i = threadIdx.x; i < 1024; i += 256) {
    const int r = i >> 5, k = (i & 31) << 2;
    float4 v = make_float4(0.f, 0.f, 0.f, 0.f);
    if (n0 + r < N) v = *(const float4*)(nf + (size_t)(n0 + r) * 128 + k);
    *(float4*)(&sNf[r * 128 + k]) = v;
  }
  __syncthreads();
  const int c = threadIdx.x & 127, g = threadIdx.x >> 7;
  const float4* w0p = (const float4*)(Wg + (size_t)c * 384);
  const float4* w1p = (const float4*)(Wg + (size_t)c * 384 + 128);
  const float4* w2p = (const float4*)(Ws + (size_t)c * 128);
  const float4* w3p = (const float4*)(Wd + (size_t)c * 128);
  float a0[16], a1[16], a2[16], a3[16];
#pragma unroll
  for (int n = 0; n < 16; ++n) { a0[n] = 0.f; a1[n] = 0.f; a2[n] = 0.f; a3[n] = 0.f; }
#pragma unroll 4
  for (int k4 = 0; k4 < 32; ++k4) {
    const float4 w0 = w0p[k4], w1 = w1p[k4], w2 = w2p[k4], w3 = w3p[k4];
#pragma unroll
    for (int n = 0; n < 16; ++n) {
      const float4 x = *(const float4*)(&sNf[(g * 16 + n) * 128 + (k4 << 2)]);
      a0[n] += x.x * w0.x + x.y * w0.y + x.z * w0.z + x.w * w0.w;
      a1[n] += x.x * w1.x + x.y * w1.y + x.z * w1.z + x.w * w1.w;
      a2[n] += x.x * w2.x + x.y * w2.y + x.z * w2.z + x.w * w2.w;
      a3[n] += x.x * w3.x + x.y * w3.y + x.z * w3.z + x.w * w3.w;
    }
  }
  const float bsv = bs[c], bdv = bd[c];
#pragma unroll
  for (int n = 0; n < 16; ++n) {
    const int node = n0 + g * 16 + n;
    if (node < N) {
      const size_t o = (size_t)node * 128 + c;
      A[o] = a0[n];
      Bm[o] = a1[n];
      S[o] = a2[n] + bsv;
      D[o] = a3[n] + bdv;
    }
  }
}

// ---------------------------------------------------------------------------
// CSR build: histogram of src, exclusive scan, scatter edge ids
// ---------------------------------------------------------------------------
__global__ __launch_bounds__(256) void hist_k(const int* __restrict__ src,
                                              int* __restrict__ cnt, int E) {
  const int stride = gridDim.x * 256;
  for (int e = blockIdx.x * 256 + threadIdx.x; e < E; e += stride)
    atomicAdd(&cnt[src[e]], 1);
}

__global__ __launch_bounds__(1024) void scan_k(const int* __restrict__ cnt,
                                               int* __restrict__ off,
                                               int* __restrict__ cur, int N) {
  __shared__ int s[1024];
  const int tid = threadIdx.x;
  const int per = (N + 1023) >> 10;
  const int base = tid * per;
  int mysum = 0;
  for (int j = 0; j < per; ++j) {
    const int i = base + j;
    if (i < N) mysum += cnt[i];
  }
  s[tid] = mysum;
  __syncthreads();
  for (int d = 1; d < 1024; d <<= 1) {
    int v = 0;
    if (tid >= d) v = s[tid - d];
    __syncthreads();
    s[tid] += v;
    __syncthreads();
  }
  int run = s[tid] - mysum;  // exclusive base for this chunk
  for (int j = 0; j < per; ++j) {
    const int i = base + j;
    if (i < N) { off[i] = run; cur[i] = run; run += cnt[i]; }
  }
  if (tid == 1023) off[N] = s[1023];
}

__global__ __launch_bounds__(256) void scatter_k(const int* __restrict__ src,
                                                 int* __restrict__ cur,
                                                 int* __restrict__ list, int E) {
  const int stride = gridDim.x * 256;
  for (int e = blockIdx.x * 256 + threadIdx.x; e < E; e += stride) {
    const int p = atomicAdd(&cur[src[e]], 1);
    list[p] = e;
  }
}

// ---------------------------------------------------------------------------
// Edge linear pass (single pass over edges):
//   lin[e,c] = (ef[e]@W3^T)[c] + A[src[e],c] + Bm[dst[e],c]  -> written to linbuf
//   accumulate per-feature sum/sumsq of lin for edge BN.
// MFMA 16x16x32 bf16. 4 waves/block, 64 edges/tile, wave w -> edges [16w,16w+16).
// A-fragments loaded register-direct from global ef (no ef LDS tile, no
// per-tile barriers). LDS = W3 only (34.8 KB) -> 4 blocks/CU.
// ---------------------------------------------------------------------------
__global__ __launch_bounds__(256, 4) void edge_lin_k(
    const int* __restrict__ ei, const float* __restrict__ ef,
    const float* __restrict__ Wg,
    const float* __restrict__ A, const float* __restrict__ Bm,
    float* __restrict__ lin, float* __restrict__ esum, float* __restrict__ esq,
    int E, int numTiles) {
  __shared__ __align__(16) short sW[128 * 136];  // pad 128->136: 2-way banks (free)

  const int tid = threadIdx.x;
  const int lane = tid & 63, wv = tid >> 6;
  const int l15 = lane & 15, quad = lane >> 4;
  const int r0 = wv << 4;
  const int* __restrict__ srcI = ei;
  const int* __restrict__ dstI = ei + E;

  // stage W3 = Wg[:,256:384] as bf16, once per block
  for (int i = tid; i < 4096; i += 256) {
    const int c = i >> 5, k = (i & 31) << 2;
    const float4 v = *(const float4*)(Wg + (size_t)c * 384 + 256 + k);
    *(short4*)(&sW[c * 136 + k]) = make_short4((short)f2bf(v.x), (short)f2bf(v.y),
                                               (short)f2bf(v.z), (short)f2bf(v.w));
  }
  __syncthreads();

  float sAc[8], qAc[8];
#pragma unroll
  for (int t = 0; t < 8; ++t) { sAc[t] = 0.f; qAc[t] = 0.f; }

  for (int tile = blockIdx.x; tile < numTiles; tile += gridDim.x) {
    const int e0 = tile << 6;
    // A-frag rows: er = e0 + r0 + l15; lane reads k = k0*32 + quad*8 .. +8
    const int er = e0 + r0 + l15;
    const bool rvalid = (er < E);
    const float* __restrict__ efr = ef + (size_t)er * 128 + quad * 8;
    bf16x8 afr[4];
#pragma unroll
    for (int k0 = 0; k0 < 4; ++k0) {
      float4 u = make_float4(0.f, 0.f, 0.f, 0.f), v = make_float4(0.f, 0.f, 0.f, 0.f);
      if (rvalid) {
        u = *(const float4*)(efr + k0 * 32);
        v = *(const float4*)(efr + k0 * 32 + 4);
      }
      bf16x8 a;
      a[0] = (short)f2bf(u.x); a[1] = (short)f2bf(u.y);
      a[2] = (short)f2bf(u.z); a[3] = (short)f2bf(u.w);
      a[4] = (short)f2bf(v.x); a[5] = (short)f2bf(v.y);
      a[6] = (short)f2bf(v.z); a[7] = (short)f2bf(v.w);
      afr[k0] = a;
    }

    f32x4 acc[8];
#pragma unroll
    for (int t = 0; t < 8; ++t) acc[t] = (f32x4){0.f, 0.f, 0.f, 0.f};
#pragma unroll
    for (int k0 = 0; k0 < 4; ++k0) {
#pragma unroll
      for (int t = 0; t < 8; ++t) {
        const bf16x8 b = *(const bf16x8*)(&sW[(t * 16 + l15) * 136 + k0 * 32 + quad * 8]);
        acc[t] = __builtin_amdgcn_mfma_f32_16x16x32_bf16(afr[k0], b, acc[t], 0, 0, 0);
      }
    }

    // C/D layout: col = l15 (feature), row = quad*4 + i (edge)
#pragma unroll
    for (int i = 0; i < 4; ++i) {
      const int rl = r0 + quad * 4 + i;
      const int e = e0 + rl;
      if (e < E) {
        const int sN = srcI[e], dN = dstI[e];
        const float* __restrict__ Ar = A + (size_t)sN * 128;
        const float* __restrict__ Br = Bm + (size_t)dN * 128;
        float* __restrict__ Lr = lin + (size_t)e * 128;
#pragma unroll
        for (int t = 0; t < 8; ++t) {
          const int c = t * 16 + l15;
          const float l = acc[t][i] + Ar[c] + Br[c];
          Lr[c] = l;
          sAc[t] += l;
          qAc[t] += l * l;
        }
      }
    }
  }

  // block-reduce stats (reuse sW as float scratch)
  __syncthreads();
  float* red = (float*)sW;
#pragma unroll
  for (int t = 0; t < 8; ++t) {
    float s = sAc[t], q = qAc[t];
    s += __shfl_xor(s, 16); s += __shfl_xor(s, 32);
    q += __shfl_xor(q, 16); q += __shfl_xor(q, 32);
    if (quad == 0) {
      red[wv * 128 + t * 16 + l15] = s;
      red[512 + wv * 128 + t * 16 + l15] = q;
    }
  }
  __syncthreads();
  if (tid < 128) {
    const float s = red[tid] + red[128 + tid] + red[256 + tid] + red[384 + tid];
    const float q = red[512 + tid] + red[640 + tid] + red[768 + tid] + red[896 + tid];
    unsafeAtomicAdd(&esum[tid], s);
    unsafeAtomicAdd(&esq[tid], q);
  }
}

// ---------------------------------------------------------------------------
__global__ __launch_bounds__(128) void finalize_bn_k(
    const float* __restrict__ sum, const float* __restrict__ sq,
    const float* __restrict__ gamma, const float* __restrict__ beta,
    float inv_cnt, float* __restrict__ scale, float* __restrict__ shift) {
  const int c = threadIdx.x;
  const float mean = sum[c] * inv_cnt;
  const float var = sq[c] * inv_cnt - mean * mean;
  const float sc = gamma[c] * rsqrtf(var + 1e-5f);
  scale[c] = sc;
  shift[c] = beta[c] - mean * sc;
}

// ---------------------------------------------------------------------------
// Node aggregation via CSR (one wave per node, 2 features per lane):
//   per edge e of node n: ue = silu(lin[e]*scE+shE)  (written in place -> outE),
//   sg = sigm(ue); agg += sg; tac += sg * D[dst[e]]   (registers, no atomics)
//   hvec[n] = S[n] + tac/(agg+eps); accumulate node BN stats.
// ---------------------------------------------------------------------------
__global__ __launch_bounds__(256) void node_agg_k(
    float* __restrict__ ue,  // in: lin, out: ue (in place)
    const int* __restrict__ list, const int* __restrict__ off,
    const int* __restrict__ dstI, const float* __restrict__ D,
    const float* __restrict__ S,
    const float* __restrict__ scE, const float* __restrict__ shE,
    float* __restrict__ hvec, float* __restrict__ nsum, float* __restrict__ nsq,
    int N) {
  const int tid = threadIdx.x;
  const int lane = tid & 63, wv = tid >> 6;
  const int c0 = lane << 1;
  const int nw = gridDim.x << 2;
  const float2 sc = *(const float2*)(scE + c0);
  const float2 sh = *(const float2*)(shE + c0);
  float psx = 0.f, psy = 0.f, pqx = 0.f, pqy = 0.f;

  for (int n = (blockIdx.x << 2) + wv; n < N; n += nw) {
    const int o0 = off[n], o1 = off[n + 1];
    float agx = 0.f, agy = 0.f, tcx = 0.f, tcy = 0.f;
    for (int i = o0; i < o1; ++i) {
      const int e = list[i];        // wave-uniform
      const int d = dstI[e];        // wave-uniform
      const float2 u = *(const float2*)(ue + (size_t)e * 128 + c0);
      const float2 g = *(const float2*)(D + (size_t)d * 128 + c0);
      const float yx = u.x * sc.x + sh.x;
      const float yy = u.y * sc.y + sh.y;
      const float uex = yx * sigm(yx);
      const float uey = yy * sigm(yy);
      *(float2*)(ue + (size_t)e * 128 + c0) = make_float2(uex, uey);
      const float sgx = sigm(uex), sgy = sigm(uey);
      agx += sgx; agy += sgy;
      tcx += sgx * g.x; tcy += sgy * g.y;
    }
    const float2 sv = *(const float2*)(S + (size_t)n * 128 + c0);
    const float hx = sv.x + tcx / (agx + 1e-6f);
    const float hy = sv.y + tcy / (agy + 1e-6f);
    *(float2*)(hvec + (size_t)n * 128 + c0) = make_float2(hx, hy);
    psx += hx; psy += hy;
    pqx += hx * hx; pqy += hy * hy;
  }

  __shared__ float red[1024];
  red[wv * 128 + c0] = psx;
  red[wv * 128 + c0 + 1] = psy;
  red[512 + wv * 128 + c0] = pqx;
  red[512 + wv * 128 + c0 + 1] = pqy;
  __syncthreads();
  if (tid < 128) {
    const float s = red[tid] + red[128 + tid] + red[256 + tid] + red[384 + tid];
    const float q = red[512 + tid] + red[640 + tid] + red[768 + tid] + red[896 + tid];
    unsafeAtomicAdd(&nsum[tid], s);
    unsafeAtomicAdd(&nsq[tid], q);
  }
}

__global__ __launch_bounds__(256) void node_out_k(
    const float* __restrict__ nf, const float* __restrict__ hvec,
    const float* __restrict__ scale, const float* __restrict__ shift,
    float* __restrict__ out, int total) {
  const int stride = gridDim.x * 256;
  for (int idx = blockIdx.x * 256 + threadIdx.x; idx < total; idx += stride) {
    const int h = idx & 127;
    const float y = hvec[idx] * scale[h] + shift[h];
    out[idx] = nf[idx] + y * sigm(y);
  }
}

// ---------------------------------------------------------------------------
extern "C" void kernel_launch(void* const* d_in, const int* in_sizes, int n_in,
                              void* d_out, int out_size, void* d_ws, size_t ws_size,
                              hipStream_t stream) {
  const int* ei = (const int*)d_in[0];
  const float* nf = (const float*)d_in[1];
  const float* ef = (const float*)d_in[2];
  const float* Wg = (const float*)d_in[3];
  // d_in[4] = bg : cancels exactly under BN mean subtraction — unused
  const float* Ws = (const float*)d_in[5];
  const float* bs = (const float*)d_in[6];
  const float* Wd = (const float*)d_in[7];
  const float* bd = (const float*)d_in[8];
  const float* zg = (const float*)d_in[9];
  const float* zb = (const float*)d_in[10];
  const float* ng = (const float*)d_in[11];
  const float* nb = (const float*)d_in[12];

  const int N = in_sizes[1] / 128;
  const int E = in_sizes[2] / 128;
  const size_t NH = (size_t)N * 128;

  float* ws = (float*)d_ws;
  float* A    = ws;
  float* Bm   = A + NH;
  float* S    = Bm + NH;
  float* D    = S + NH;
  float* hvec = D + NH;
  float* st   = hvec + NH;  // 1024 floats of stats/params
  float* esum = st;
  float* esq  = st + 128;
  float* nsum = st + 256;
  float* nsq  = st + 384;
  float* scE  = st + 512;
  float* shE  = st + 640;
  float* scN  = st + 768;
  float* shN  = st + 896;
  int* cnt  = (int*)(st + 1024);   // [N]
  int* off  = cnt + N;             // [N+1]
  int* cur  = off + N + 1;         // [N]
  int* list = cur + N;             // [E]

  float* outN = (float*)d_out;
  float* outE = outN + NH;  // used as lin scratch, then final ue

  // zero: stats block (1024 floats) + histogram (N ints), contiguous
  hipMemsetAsync(st, 0, (size_t)(1024 + N) * sizeof(float), stream);

  node_gemm_k<<<(N + 31) / 32, 256, 0, stream>>>(nf, Wg, Ws, bs, Wd, bd, A, Bm, S, D, N);

  hist_k<<<640, 256, 0, stream>>>(ei, cnt, E);
  scan_k<<<1, 1024, 0, stream>>>(cnt, off, cur, N);
  scatter_k<<<640, 256, 0, stream>>>(ei, cur, list, E);

  const int numTiles = (E + 63) / 64;
  const int gblocks = numTiles < 1024 ? numTiles : 1024;
  edge_lin_k<<<gblocks, 256, 0, stream>>>(ei, ef, Wg, A, Bm, outE, esum, esq, E, numTiles);
  finalize_bn_k<<<1, 128, 0, stream>>>(esum, esq, zg, zb, 1.0f / (float)E, scE, shE);

  node_agg_k<<<(N + 3) / 4, 256, 0, stream>>>(outE, list, off, ei + E, D, S, scE, shE,
                                              hvec, nsum, nsq, N);
  finalize_bn_k<<<1, 128, 0, stream>>>(nsum, nsq, ng, nb, 1.0f / (float)N, scN, shN);
  node_out_k<<<640, 256, 0, stream>>>(nf, hvec, scN, shN, outN, (int)NH);
}

// Round 2
// 1159.566 us; speedup vs baseline: 1.3478x; 1.0540x over previous
//
#include <hip/hip_runtime.h>
#include <cstddef>

#define DEVINL __device__ __forceinline__

typedef _Float16 f16;
typedef __attribute__((ext_vector_type(2))) _Float16 f16x2;
typedef __attribute__((ext_vector_type(8))) short bf16x8;
typedef __attribute__((ext_vector_type(4))) float f32x4;
typedef __attribute__((ext_vector_type(2))) float f32x2;

DEVINL unsigned short f2bf(float f) {
  unsigned int u = __builtin_bit_cast(unsigned int, f);
  u += 0x7FFFu + ((u >> 16) & 1u);
  return (unsigned short)(u >> 16);
}

DEVINL float sigm(float x) { return 1.0f / (1.0f + __expf(-x)); }

// ---------------------------------------------------------------------------
// Node GEMMs: Ah = nf@Wg1^T, Bh = nf@Wg2^T (f16), S = nf@Ws^T + bs (f32),
// Dh = nf@Wd^T + bd (f16).  bg cancels under BN mean subtraction.
// ---------------------------------------------------------------------------
__global__ __launch_bounds__(256) void node_gemm_k(
    const float* __restrict__ nf, const float* __restrict__ Wg,
    const float* __restrict__ Ws, const float* __restrict__ bs,
    const float* __restrict__ Wd, const float* __restrict__ bd,
    f16* __restrict__ Ah, f16* __restrict__ Bh,
    float* __restrict__ S, f16* __restrict__ Dh, int N) {
  __shared__ float sNf[32 * 128];
  const int n0 = blockIdx.x * 32;
  for (int i = threadIdx.x; i < 1024; i += 256) {
    const int r = i >> 5, k = (i & 31) << 2;
    float4 v = make_float4(0.f, 0.f, 0.f, 0.f);
    if (n0 + r < N) v = *(const float4*)(nf + (size_t)(n0 + r) * 128 + k);
    *(float4*)(&sNf[r * 128 + k]) = v;
  }
  __syncthreads();
  const int c = threadIdx.x & 127, g = threadIdx.x >> 7;
  const float4* w0p = (const float4*)(Wg + (size_t)c * 384);
  const float4* w1p = (const float4*)(Wg + (size_t)c * 384 + 128);
  const float4* w2p = (const float4*)(Ws + (size_t)c * 128);
  const float4* w3p = (const float4*)(Wd + (size_t)c * 128);
  float a0[16], a1[16], a2[16], a3[16];
#pragma unroll
  for (int n = 0; n < 16; ++n) { a0[n] = 0.f; a1[n] = 0.f; a2[n] = 0.f; a3[n] = 0.f; }
#pragma unroll 4
  for (int k4 = 0; k4 < 32; ++k4) {
    const float4 w0 = w0p[k4], w1 = w1p[k4], w2 = w2p[k4], w3 = w3p[k4];
#pragma unroll
    for (int n = 0; n < 16; ++n) {
      const float4 x = *(const float4*)(&sNf[(g * 16 + n) * 128 + (k4 << 2)]);
      a0[n] += x.x * w0.x + x.y * w0.y + x.z * w0.z + x.w * w0.w;
      a1[n] += x.x * w1.x + x.y * w1.y + x.z * w1.z + x.w * w1.w;
      a2[n] += x.x * w2.x + x.y * w2.y + x.z * w2.z + x.w * w2.w;
      a3[n] += x.x * w3.x + x.y * w3.y + x.z * w3.z + x.w * w3.w;
    }
  }
  const float bsv = bs[c], bdv = bd[c];
#pragma unroll
  for (int n = 0; n < 16; ++n) {
    const int node = n0 + g * 16 + n;
    if (node < N) {
      const size_t o = (size_t)node * 128 + c;
      Ah[o] = (f16)a0[n];
      Bh[o] = (f16)a1[n];
      S[o] = a2[n] + bsv;
      Dh[o] = (f16)(a3[n] + bdv);
    }
  }
}

// ---------------------------------------------------------------------------
// CSR build: histogram of src, exclusive scan, scatter edge ids
// ---------------------------------------------------------------------------
__global__ __launch_bounds__(256) void hist_k(const int* __restrict__ src,
                                              int* __restrict__ cnt, int E) {
  const int stride = gridDim.x * 256;
  for (int e = blockIdx.x * 256 + threadIdx.x; e < E; e += stride)
    atomicAdd(&cnt[src[e]], 1);
}

__global__ __launch_bounds__(1024) void scan_k(const int* __restrict__ cnt,
                                               int* __restrict__ off,
                                               int* __restrict__ cur, int N) {
  __shared__ int s[1024];
  const int tid = threadIdx.x;
  const int per = (N + 1023) >> 10;
  const int base = tid * per;
  int mysum = 0;
  for (int j = 0; j < per; ++j) {
    const int i = base + j;
    if (i < N) mysum += cnt[i];
  }
  s[tid] = mysum;
  __syncthreads();
  for (int d = 1; d < 1024; d <<= 1) {
    int v = 0;
    if (tid >= d) v = s[tid - d];
    __syncthreads();
    s[tid] += v;
    __syncthreads();
  }
  int run = s[tid] - mysum;  // exclusive base for this chunk
  for (int j = 0; j < per; ++j) {
    const int i = base + j;
    if (i < N) { off[i] = run; cur[i] = run; run += cnt[i]; }
  }
  if (tid == 1023) off[N] = s[1023];
}

__global__ __launch_bounds__(256) void scatter_k(const int* __restrict__ src,
                                                 int* __restrict__ cur,
                                                 int* __restrict__ list, int E) {
  const int stride = gridDim.x * 256;
  for (int e = blockIdx.x * 256 + threadIdx.x; e < E; e += stride) {
    const int p = atomicAdd(&cur[src[e]], 1);
    list[p] = e;
  }
}

// ---------------------------------------------------------------------------
// Edge linear pass:
//   lin[e,c] = (ef[e]@W3^T)[c] + Ah[src[e],c] + Bh[dst[e],c]
//   stored f16 (L16) into linh, else f32 into linf; per-feature sum/sumsq.
// MFMA 16x16x32 bf16; 4 waves/block; ef loaded register-direct (nontemporal,
// stream — keeps A/B gather working set L2-resident). LDS = W3 only.
// ---------------------------------------------------------------------------
template <bool L16>
__global__ __launch_bounds__(256, 4) void edge_lin_k(
    const int* __restrict__ ei, const float* __restrict__ ef,
    const float* __restrict__ Wg,
    const f16* __restrict__ Ah, const f16* __restrict__ Bh,
    f16* __restrict__ linh, float* __restrict__ linf,
    float* __restrict__ esum, float* __restrict__ esq,
    int E, int numTiles) {
  __shared__ __align__(16) short sW[128 * 136];  // pad 128->136: 2-way banks (free)

  const int tid = threadIdx.x;
  const int lane = tid & 63, wv = tid >> 6;
  const int l15 = lane & 15, quad = lane >> 4;
  const int r0 = wv << 4;
  const int* __restrict__ srcI = ei;
  const int* __restrict__ dstI = ei + E;

  // stage W3 = Wg[:,256:384] as bf16, once per block
  for (int i = tid; i < 4096; i += 256) {
    const int c = i >> 5, k = (i & 31) << 2;
    const float4 v = *(const float4*)(Wg + (size_t)c * 384 + 256 + k);
    *(short4*)(&sW[c * 136 + k]) = make_short4((short)f2bf(v.x), (short)f2bf(v.y),
                                               (short)f2bf(v.z), (short)f2bf(v.w));
  }
  __syncthreads();

  float sAc[8], qAc[8];
#pragma unroll
  for (int t = 0; t < 8; ++t) { sAc[t] = 0.f; qAc[t] = 0.f; }

  for (int tile = blockIdx.x; tile < numTiles; tile += gridDim.x) {
    const int e0 = tile << 6;
    const int er = e0 + r0 + l15;
    const bool rvalid = (er < E);
    const float* __restrict__ efr = ef + (size_t)er * 128 + quad * 8;
    bf16x8 afr[4];
#pragma unroll
    for (int k0 = 0; k0 < 4; ++k0) {
      f32x4 u = (f32x4){0.f, 0.f, 0.f, 0.f}, v = (f32x4){0.f, 0.f, 0.f, 0.f};
      if (rvalid) {
        u = __builtin_nontemporal_load((const f32x4*)(efr + k0 * 32));
        v = __builtin_nontemporal_load((const f32x4*)(efr + k0 * 32 + 4));
      }
      bf16x8 a;
      a[0] = (short)f2bf(u[0]); a[1] = (short)f2bf(u[1]);
      a[2] = (short)f2bf(u[2]); a[3] = (short)f2bf(u[3]);
      a[4] = (short)f2bf(v[0]); a[5] = (short)f2bf(v[1]);
      a[6] = (short)f2bf(v[2]); a[7] = (short)f2bf(v[3]);
      afr[k0] = a;
    }

    f32x4 acc[8];
#pragma unroll
    for (int t = 0; t < 8; ++t) acc[t] = (f32x4){0.f, 0.f, 0.f, 0.f};
#pragma unroll
    for (int k0 = 0; k0 < 4; ++k0) {
#pragma unroll
      for (int t = 0; t < 8; ++t) {
        const bf16x8 b = *(const bf16x8*)(&sW[(t * 16 + l15) * 136 + k0 * 32 + quad * 8]);
        acc[t] = __builtin_amdgcn_mfma_f32_16x16x32_bf16(afr[k0], b, acc[t], 0, 0, 0);
      }
    }

    // C/D layout: col = l15 (feature), row = quad*4 + i (edge)
#pragma unroll
    for (int i = 0; i < 4; ++i) {
      const int rl = r0 + quad * 4 + i;
      const int e = e0 + rl;
      if (e < E) {
        const int sN = srcI[e], dN = dstI[e];
        const f16* __restrict__ Ar = Ah + (size_t)sN * 128;
        const f16* __restrict__ Br = Bh + (size_t)dN * 128;
#pragma unroll
        for (int t = 0; t < 8; ++t) {
          const int c = t * 16 + l15;
          const float l = acc[t][i] + (float)Ar[c] + (float)Br[c];
          if (L16) {
            __builtin_nontemporal_store((f16)l, linh + (size_t)e * 128 + c);
          } else {
            __builtin_nontemporal_store(l, linf + (size_t)e * 128 + c);
          }
          sAc[t] += l;
          qAc[t] += l * l;
        }
      }
    }
  }

  // block-reduce stats (reuse sW as float scratch)
  __syncthreads();
  float* red = (float*)sW;
#pragma unroll
  for (int t = 0; t < 8; ++t) {
    float s = sAc[t], q = qAc[t];
    s += __shfl_xor(s, 16); s += __shfl_xor(s, 32);
    q += __shfl_xor(q, 16); q += __shfl_xor(q, 32);
    if (quad == 0) {
      red[wv * 128 + t * 16 + l15] = s;
      red[512 + wv * 128 + t * 16 + l15] = q;
    }
  }
  __syncthreads();
  if (tid < 128) {
    const float s = red[tid] + red[128 + tid] + red[256 + tid] + red[384 + tid];
    const float q = red[512 + tid] + red[640 + tid] + red[768 + tid] + red[896 + tid];
    unsafeAtomicAdd(&esum[tid], s);
    unsafeAtomicAdd(&esq[tid], q);
  }
}

// ---------------------------------------------------------------------------
// Node aggregation via CSR (one wave per node, 2 features per lane).
// Edge-BN finalize recomputed per block (removes finalize kernel + bubble).
// 1-deep prefetch of (e, dst) overlaps the index chain with row loads/math.
// ---------------------------------------------------------------------------
template <bool L16>
__global__ __launch_bounds__(256) void node_agg_k(
    const f16* __restrict__ linh, float* __restrict__ outE,
    const int* __restrict__ list, const int* __restrict__ off,
    const int* __restrict__ dstI, const f16* __restrict__ Dh,
    const float* __restrict__ S,
    const float* __restrict__ esum, const float* __restrict__ esq,
    const float* __restrict__ zg, const float* __restrict__ zb, float invE,
    float* __restrict__ hvec, float* __restrict__ nsum, float* __restrict__ nsq,
    int N) {
  __shared__ float sSc[128], sSh[128];
  const int tid = threadIdx.x;
  if (tid < 128) {
    const float mean = esum[tid] * invE;
    const float var = esq[tid] * invE - mean * mean;
    const float sc = zg[tid] * rsqrtf(var + 1e-5f);
    sSc[tid] = sc;
    sSh[tid] = zb[tid] - mean * sc;
  }
  __syncthreads();

  const int lane = tid & 63, wv = tid >> 6;
  const int c0 = lane << 1;
  const int nw = gridDim.x << 2;
  const float scx = sSc[c0], scy = sSc[c0 + 1];
  const float shx = sSh[c0], shy = sSh[c0 + 1];
  float psx = 0.f, psy = 0.f, pqx = 0.f, pqy = 0.f;

  for (int n = (blockIdx.x << 2) + wv; n < N; n += nw) {
    const int o0 = off[n], o1 = off[n + 1];
    float agx = 0.f, agy = 0.f, tcx = 0.f, tcy = 0.f;
    int e = 0, d = 0;
    if (o0 < o1) { e = list[o0]; d = dstI[e]; }
    for (int i = o0; i < o1; ++i) {
      float lx, ly;
      if (L16) {
        const f16x2 u = __builtin_nontemporal_load((const f16x2*)(linh + (size_t)e * 128 + c0));
        lx = (float)u.x; ly = (float)u.y;
      } else {
        const f32x2 u = __builtin_nontemporal_load((const f32x2*)(outE + (size_t)e * 128 + c0));
        lx = u.x; ly = u.y;
      }
      const f16x2 g = *(const f16x2*)(Dh + (size_t)d * 128 + c0);
      const int ec = e;
      if (i + 1 < o1) { e = list[i + 1]; d = dstI[e]; }  // prefetch next indices
      const float yx = lx * scx + shx, yy = ly * scy + shy;
      const float uex = yx * sigm(yx), uey = yy * sigm(yy);
      __builtin_nontemporal_store((f32x2){uex, uey}, (f32x2*)(outE + (size_t)ec * 128 + c0));
      const float sgx = sigm(uex), sgy = sigm(uey);
      agx += sgx; agy += sgy;
      tcx += sgx * (float)g.x; tcy += sgy * (float)g.y;
    }
    const f32x2 sv = *(const f32x2*)(S + (size_t)n * 128 + c0);
    const float hx = sv.x + tcx / (agx + 1e-6f);
    const float hy = sv.y + tcy / (agy + 1e-6f);
    __builtin_nontemporal_store((f32x2){hx, hy}, (f32x2*)(hvec + (size_t)n * 128 + c0));
    psx += hx; psy += hy;
    pqx += hx * hx; pqy += hy * hy;
  }

  __shared__ float red[1024];
  red[wv * 128 + c0] = psx;
  red[wv * 128 + c0 + 1] = psy;
  red[512 + wv * 128 + c0] = pqx;
  red[512 + wv * 128 + c0 + 1] = pqy;
  __syncthreads();
  if (tid < 128) {
    const float s = red[tid] + red[128 + tid] + red[256 + tid] + red[384 + tid];
    const float q = red[512 + tid] + red[640 + tid] + red[768 + tid] + red[896 + tid];
    unsafeAtomicAdd(&nsum[tid], s);
    unsafeAtomicAdd(&nsq[tid], q);
  }
}

// ---------------------------------------------------------------------------
__global__ __launch_bounds__(256) void node_out_k(
    const float* __restrict__ nf, const float* __restrict__ hvec,
    const float* __restrict__ nsum, const float* __restrict__ nsq,
    const float* __restrict__ ng, const float* __restrict__ nb, float invN,
    float* __restrict__ out, int total) {
  __shared__ float sSc[128], sSh[128];
  if (threadIdx.x < 128) {
    const int c = threadIdx.x;
    const float mean = nsum[c] * invN;
    const float var = nsq[c] * invN - mean * mean;
    const float sc = ng[c] * rsqrtf(var + 1e-5f);
    sSc[c] = sc;
    sSh[c] = nb[c] - mean * sc;
  }
  __syncthreads();
  const int stride = gridDim.x * 256;
  for (int idx = blockIdx.x * 256 + threadIdx.x; idx < total; idx += stride) {
    const int h = idx & 127;
    const float y = __builtin_nontemporal_load(hvec + idx) * sSc[h] + sSh[h];
    const float o = __builtin_nontemporal_load(nf + idx) + y * sigm(y);
    __builtin_nontemporal_store(o, out + idx);
  }
}

// ---------------------------------------------------------------------------
extern "C" void kernel_launch(void* const* d_in, const int* in_sizes, int n_in,
                              void* d_out, int out_size, void* d_ws, size_t ws_size,
                              hipStream_t stream) {
  const int* ei = (const int*)d_in[0];
  const float* nf = (const float*)d_in[1];
  const float* ef = (const float*)d_in[2];
  const float* Wg = (const float*)d_in[3];
  // d_in[4] = bg : cancels exactly under BN mean subtraction — unused
  const float* Ws = (const float*)d_in[5];
  const float* bs = (const float*)d_in[6];
  const float* Wd = (const float*)d_in[7];
  const float* bd = (const float*)d_in[8];
  const float* zg = (const float*)d_in[9];
  const float* zb = (const float*)d_in[10];
  const float* ng = (const float*)d_in[11];
  const float* nb = (const float*)d_in[12];

  const int N = in_sizes[1] / 128;
  const int E = in_sizes[2] / 128;
  const size_t NH = (size_t)N * 128;

  char* p = (char*)d_ws;
  auto alloc = [&](size_t bytes) {
    char* r = p;
    p += (bytes + 255) & ~(size_t)255;
    return r;
  };
  float* S    = (float*)alloc(NH * 4);
  float* hvec = (float*)alloc(NH * 4);
  f16* Ah = (f16*)alloc(NH * 2);
  f16* Bh = (f16*)alloc(NH * 2);
  f16* Dh = (f16*)alloc(NH * 2);
  float* st = (float*)alloc(1024 * 4);  // esum,esq,nsum,nsq (512 used)
  float* esum = st;
  float* esq  = st + 128;
  float* nsum = st + 256;
  float* nsq  = st + 384;
  int* cnt  = (int*)alloc((size_t)N * 4);
  int* off  = (int*)alloc((size_t)(N + 1) * 4);
  int* cur  = (int*)alloc((size_t)N * 4);
  int* list = (int*)alloc((size_t)E * 4);
  f16* linh = (f16*)p;
  const bool L16 =
      ((size_t)(p - (char*)d_ws) + (size_t)E * 128 * 2) <= ws_size;

  float* outN = (float*)d_out;
  float* outE = outN + NH;  // f32-lin scratch (fallback path), then final ue

  // zero: stats block + cnt (contiguous span incl. padding)
  hipMemsetAsync(st, 0, (size_t)((char*)cnt + (size_t)N * 4 - (char*)st), stream);

  node_gemm_k<<<(N + 31) / 32, 256, 0, stream>>>(nf, Wg, Ws, bs, Wd, bd, Ah, Bh, S, Dh, N);

  hist_k<<<640, 256, 0, stream>>>(ei, cnt, E);
  scan_k<<<1, 1024, 0, stream>>>(cnt, off, cur, N);
  scatter_k<<<640, 256, 0, stream>>>(ei, cur, list, E);

  const int numTiles = (E + 63) / 64;
  const int gblocks = numTiles < 1024 ? numTiles : 1024;
  if (L16) {
    edge_lin_k<true><<<gblocks, 256, 0, stream>>>(ei, ef, Wg, Ah, Bh, linh, nullptr,
                                                  esum, esq, E, numTiles);
    node_agg_k<true><<<(N + 3) / 4, 256, 0, stream>>>(
        linh, outE, list, off, ei + E, Dh, S, esum, esq, zg, zb, 1.0f / (float)E,
        hvec, nsum, nsq, N);
  } else {
    edge_lin_k<false><<<gblocks, 256, 0, stream>>>(ei, ef, Wg, Ah, Bh, nullptr, outE,
                                                   esum, esq, E, numTiles);
    node_agg_k<false><<<(N + 3) / 4, 256, 0, stream>>>(
        nullptr, outE, list, off, ei + E, Dh, S, esum, esq, zg, zb, 1.0f / (float)E,
        hvec, nsum, nsq, N);
  }
  node_out_k<<<640, 256, 0, stream>>>(nf, hvec, nsum, nsq, ng, nb, 1.0f / (float)N,
                                      outN, (int)NH);
}

// Round 3
// 1152.475 us; speedup vs baseline: 1.3561x; 1.0062x over previous
//
#include <hip/hip_runtime.h>
#include <cstddef>

#define DEVINL __device__ __forceinline__

typedef _Float16 f16;
typedef __attribute__((ext_vector_type(2))) _Float16 f16x2;
typedef __attribute__((ext_vector_type(8))) short bf16x8;
typedef __attribute__((ext_vector_type(4))) float f32x4;
typedef __attribute__((ext_vector_type(2))) float f32x2;

DEVINL unsigned short f2bf(float f) {
  unsigned int u = __builtin_bit_cast(unsigned int, f);
  u += 0x7FFFu + ((u >> 16) & 1u);
  return (unsigned short)(u >> 16);
}

DEVINL float sigm(float x) { return 1.0f / (1.0f + __expf(-x)); }

// ---------------------------------------------------------------------------
// Node GEMMs: Ah = nf@Wg1^T, Bh = nf@Wg2^T (f16), S = nf@Ws^T + bs (f32),
// Dh = nf@Wd^T + bd (f16).  bg cancels under BN mean subtraction.
// ---------------------------------------------------------------------------
__global__ __launch_bounds__(256) void node_gemm_k(
    const float* __restrict__ nf, const float* __restrict__ Wg,
    const float* __restrict__ Ws, const float* __restrict__ bs,
    const float* __restrict__ Wd, const float* __restrict__ bd,
    f16* __restrict__ Ah, f16* __restrict__ Bh,
    float* __restrict__ S, f16* __restrict__ Dh, int N) {
  __shared__ float sNf[32 * 128];
  const int n0 = blockIdx.x * 32;
  for (int i = threadIdx.x; i < 1024; i += 256) {
    const int r = i >> 5, k = (i & 31) << 2;
    float4 v = make_float4(0.f, 0.f, 0.f, 0.f);
    if (n0 + r < N) v = *(const float4*)(nf + (size_t)(n0 + r) * 128 + k);
    *(float4*)(&sNf[r * 128 + k]) = v;
  }
  __syncthreads();
  const int c = threadIdx.x & 127, g = threadIdx.x >> 7;
  const float4* w0p = (const float4*)(Wg + (size_t)c * 384);
  const float4* w1p = (const float4*)(Wg + (size_t)c * 384 + 128);
  const float4* w2p = (const float4*)(Ws + (size_t)c * 128);
  const float4* w3p = (const float4*)(Wd + (size_t)c * 128);
  float a0[16], a1[16], a2[16], a3[16];
#pragma unroll
  for (int n = 0; n < 16; ++n) { a0[n] = 0.f; a1[n] = 0.f; a2[n] = 0.f; a3[n] = 0.f; }
#pragma unroll 4
  for (int k4 = 0; k4 < 32; ++k4) {
    const float4 w0 = w0p[k4], w1 = w1p[k4], w2 = w2p[k4], w3 = w3p[k4];
#pragma unroll
    for (int n = 0; n < 16; ++n) {
      const float4 x = *(const float4*)(&sNf[(g * 16 + n) * 128 + (k4 << 2)]);
      a0[n] += x.x * w0.x + x.y * w0.y + x.z * w0.z + x.w * w0.w;
      a1[n] += x.x * w1.x + x.y * w1.y + x.z * w1.z + x.w * w1.w;
      a2[n] += x.x * w2.x + x.y * w2.y + x.z * w2.z + x.w * w2.w;
      a3[n] += x.x * w3.x + x.y * w3.y + x.z * w3.z + x.w * w3.w;
    }
  }
  const float bsv = bs[c], bdv = bd[c];
#pragma unroll
  for (int n = 0; n < 16; ++n) {
    const int node = n0 + g * 16 + n;
    if (node < N) {
      const size_t o = (size_t)node * 128 + c;
      Ah[o] = (f16)a0[n];
      Bh[o] = (f16)a1[n];
      S[o] = a2[n] + bsv;
      Dh[o] = (f16)(a3[n] + bdv);
    }
  }
}

// ---------------------------------------------------------------------------
// CSR build: histogram of src, exclusive scan, scatter (edge id, dst) + src
// ---------------------------------------------------------------------------
__global__ __launch_bounds__(256) void hist_k(const int* __restrict__ src,
                                              int* __restrict__ cnt, int E) {
  const int stride = gridDim.x * 256;
  for (int e = blockIdx.x * 256 + threadIdx.x; e < E; e += stride)
    atomicAdd(&cnt[src[e]], 1);
}

__global__ __launch_bounds__(1024) void scan_k(const int* __restrict__ cnt,
                                               int* __restrict__ off,
                                               int* __restrict__ cur, int N) {
  __shared__ int s[1024];
  const int tid = threadIdx.x;
  const int per = (N + 1023) >> 10;
  const int base = tid * per;
  int mysum = 0;
  for (int j = 0; j < per; ++j) {
    const int i = base + j;
    if (i < N) mysum += cnt[i];
  }
  s[tid] = mysum;
  __syncthreads();
  for (int d = 1; d < 1024; d <<= 1) {
    int v = 0;
    if (tid >= d) v = s[tid - d];
    __syncthreads();
    s[tid] += v;
    __syncthreads();
  }
  int run = s[tid] - mysum;  // exclusive base for this chunk
  for (int j = 0; j < per; ++j) {
    const int i = base + j;
    if (i < N) {
      const int cv = cnt[i];
      off[i] = run; cur[i] = run; run += cv;
    }
  }
  if (tid == 1023) off[N] = s[1023];
}

__global__ __launch_bounds__(256) void scatter_k(const int* __restrict__ src,
                                                 const int* __restrict__ dst,
                                                 int* __restrict__ cur,
                                                 int2* __restrict__ ed,
                                                 int* __restrict__ ssrc, int E) {
  const int stride = gridDim.x * 256;
  for (int e = blockIdx.x * 256 + threadIdx.x; e < E; e += stride) {
    const int s = src[e];
    const int p = atomicAdd(&cur[s], 1);
    ed[p] = make_int2(e, dst[e]);
    ssrc[p] = s;
  }
}

// ---------------------------------------------------------------------------
// Edge linear pass over CSR POSITIONS (CSRORD=1):
//   for position i: e = ed[i].x, lin = (ef[e]@W3^T) + Ah[ssrc[i]] + Bh[ed[i].y]
//   stored f16 at CSR position i into linh (node_agg then reads it as a
//   sequential stream). Ah gather is sequential w/ ~deg-fold L1 reuse.
// Fallback (CSRORD=0): original-order edges, f32 lin into linf (= outE).
// MFMA 16x16x32 bf16; 4 waves/block; per-feature sum/sumsq accumulated.
// ---------------------------------------------------------------------------
template <bool CSRORD>
__global__ __launch_bounds__(256, 4) void edge_lin_k(
    const int* __restrict__ ei, const float* __restrict__ ef,
    const float* __restrict__ Wg,
    const f16* __restrict__ Ah, const f16* __restrict__ Bh,
    const int2* __restrict__ ed, const int* __restrict__ ssrc,
    f16* __restrict__ linh, float* __restrict__ linf,
    float* __restrict__ esum, float* __restrict__ esq,
    int E, int numTiles) {
  __shared__ __align__(16) short sW[128 * 136];  // pad 128->136: 2-way banks (free)

  const int tid = threadIdx.x;
  const int lane = tid & 63, wv = tid >> 6;
  const int l15 = lane & 15, quad = lane >> 4;
  const int r0 = wv << 4;
  const int* __restrict__ srcI = ei;
  const int* __restrict__ dstI = ei + E;

  // stage W3 = Wg[:,256:384] as bf16, once per block
  for (int i = tid; i < 4096; i += 256) {
    const int c = i >> 5, k = (i & 31) << 2;
    const float4 v = *(const float4*)(Wg + (size_t)c * 384 + 256 + k);
    *(short4*)(&sW[c * 136 + k]) = make_short4((short)f2bf(v.x), (short)f2bf(v.y),
                                               (short)f2bf(v.z), (short)f2bf(v.w));
  }
  __syncthreads();

  float sAc[8], qAc[8];
#pragma unroll
  for (int t = 0; t < 8; ++t) { sAc[t] = 0.f; qAc[t] = 0.f; }

  for (int tile = blockIdx.x; tile < numTiles; tile += gridDim.x) {
    const int p0 = tile << 6;
    // A-frag rows: CSR position idx -> edge e (random ef row, full 512B lines)
    const int idxr = p0 + r0 + l15;
    const bool rvalid = (idxr < E);
    int erow = 0;
    if (rvalid) erow = CSRORD ? ed[idxr].x : idxr;
    const float* __restrict__ efr = ef + (size_t)erow * 128 + quad * 8;
    bf16x8 afr[4];
#pragma unroll
    for (int k0 = 0; k0 < 4; ++k0) {
      f32x4 u = (f32x4){0.f, 0.f, 0.f, 0.f}, v = (f32x4){0.f, 0.f, 0.f, 0.f};
      if (rvalid) {
        u = __builtin_nontemporal_load((const f32x4*)(efr + k0 * 32));
        v = __builtin_nontemporal_load((const f32x4*)(efr + k0 * 32 + 4));
      }
      bf16x8 a;
      a[0] = (short)f2bf(u[0]); a[1] = (short)f2bf(u[1]);
      a[2] = (short)f2bf(u[2]); a[3] = (short)f2bf(u[3]);
      a[4] = (short)f2bf(v[0]); a[5] = (short)f2bf(v[1]);
      a[6] = (short)f2bf(v[2]); a[7] = (short)f2bf(v[3]);
      afr[k0] = a;
    }

    f32x4 acc[8];
#pragma unroll
    for (int t = 0; t < 8; ++t) acc[t] = (f32x4){0.f, 0.f, 0.f, 0.f};
#pragma unroll
    for (int k0 = 0; k0 < 4; ++k0) {
#pragma unroll
      for (int t = 0; t < 8; ++t) {
        const bf16x8 b = *(const bf16x8*)(&sW[(t * 16 + l15) * 136 + k0 * 32 + quad * 8]);
        acc[t] = __builtin_amdgcn_mfma_f32_16x16x32_bf16(afr[k0], b, acc[t], 0, 0, 0);
      }
    }

    // C/D layout: col = l15 (feature), row = quad*4 + i (position within tile)
#pragma unroll
    for (int i = 0; i < 4; ++i) {
      const int rl = r0 + quad * 4 + i;
      const int idx = p0 + rl;
      if (idx < E) {
        int sN, dN;
        if (CSRORD) {
          const int2 v = ed[idx];
          dN = v.y;
          sN = ssrc[idx];
        } else {
          sN = srcI[idx];
          dN = dstI[idx];
        }
        const f16* __restrict__ Ar = Ah + (size_t)sN * 128;
        const f16* __restrict__ Br = Bh + (size_t)dN * 128;
#pragma unroll
        for (int t = 0; t < 8; ++t) {
          const int c = t * 16 + l15;
          const float l = acc[t][i] + (float)Ar[c] + (float)Br[c];
          if (CSRORD) {
            __builtin_nontemporal_store((f16)l, linh + (size_t)idx * 128 + c);
          } else {
            __builtin_nontemporal_store(l, linf + (size_t)idx * 128 + c);
          }
          sAc[t] += l;
          qAc[t] += l * l;
        }
      }
    }
  }

  // block-reduce stats (reuse sW as float scratch)
  __syncthreads();
  float* red = (float*)sW;
#pragma unroll
  for (int t = 0; t < 8; ++t) {
    float s = sAc[t], q = qAc[t];
    s += __shfl_xor(s, 16); s += __shfl_xor(s, 32);
    q += __shfl_xor(q, 16); q += __shfl_xor(q, 32);
    if (quad == 0) {
      red[wv * 128 + t * 16 + l15] = s;
      red[512 + wv * 128 + t * 16 + l15] = q;
    }
  }
  __syncthreads();
  if (tid < 128) {
    const float s = red[tid] + red[128 + tid] + red[256 + tid] + red[384 + tid];
    const float q = red[512 + tid] + red[640 + tid] + red[768 + tid] + red[896 + tid];
    unsafeAtomicAdd(&esum[tid], s);
    unsafeAtomicAdd(&esq[tid], q);
  }
}

// ---------------------------------------------------------------------------
// Node aggregation via CSR (one wave per node, 2 features per lane).
// CSRORD=1: lin read sequentially from linh at CSR positions [o0,o1);
//           (e,dst) from packed ed (sequential 8B) -> clean 1-deep prefetch.
// CSRORD=0: lin f32 in outE at edge position, updated in place.
// Edge-BN finalize recomputed per block (no separate kernel/bubble).
// ---------------------------------------------------------------------------
template <bool CSRORD>
__global__ __launch_bounds__(256) void node_agg_k(
    const f16* __restrict__ linh, float* __restrict__ outE,
    const int2* __restrict__ ed, const int* __restrict__ off,
    const f16* __restrict__ Dh, const float* __restrict__ S,
    const float* __restrict__ esum, const float* __restrict__ esq,
    const float* __restrict__ zg, const float* __restrict__ zb, float invE,
    float* __restrict__ hvec, float* __restrict__ nsum, float* __restrict__ nsq,
    int N) {
  __shared__ float sSc[128], sSh[128];
  const int tid = threadIdx.x;
  if (tid < 128) {
    const float mean = esum[tid] * invE;
    const float var = esq[tid] * invE - mean * mean;
    const float sc = zg[tid] * rsqrtf(var + 1e-5f);
    sSc[tid] = sc;
    sSh[tid] = zb[tid] - mean * sc;
  }
  __syncthreads();

  const int lane = tid & 63, wv = tid >> 6;
  const int c0 = lane << 1;
  const int nw = gridDim.x << 2;
  const float scx = sSc[c0], scy = sSc[c0 + 1];
  const float shx = sSh[c0], shy = sSh[c0 + 1];
  float psx = 0.f, psy = 0.f, pqx = 0.f, pqy = 0.f;

  for (int n = (blockIdx.x << 2) + wv; n < N; n += nw) {
    const int o0 = off[n], o1 = off[n + 1];
    float agx = 0.f, agy = 0.f, tcx = 0.f, tcy = 0.f;
    // 1-deep software pipeline
    int e = 0;
    float lx = 0.f, ly = 0.f;
    f16x2 g = (f16x2){(f16)0.f, (f16)0.f};
    if (o0 < o1) {
      const int2 v = ed[o0];
      e = v.x;
      if (CSRORD) {
        const f16x2 u = __builtin_nontemporal_load((const f16x2*)(linh + (size_t)o0 * 128 + c0));
        lx = (float)u.x; ly = (float)u.y;
      } else {
        const f32x2 u = *(const f32x2*)(outE + (size_t)e * 128 + c0);
        lx = u.x; ly = u.y;
      }
      g = *(const f16x2*)(Dh + (size_t)v.y * 128 + c0);
    }
    for (int i = o0; i < o1; ++i) {
      const float lcx = lx, lcy = ly;
      const f16x2 gc = g;
      const int ec = e;
      if (i + 1 < o1) {
        const int2 v = ed[i + 1];
        e = v.x;
        if (CSRORD) {
          const f16x2 u = __builtin_nontemporal_load((const f16x2*)(linh + (size_t)(i + 1) * 128 + c0));
          lx = (float)u.x; ly = (float)u.y;
        } else {
          const f32x2 u = *(const f32x2*)(outE + (size_t)e * 128 + c0);
          lx = u.x; ly = u.y;
        }
        g = *(const f16x2*)(Dh + (size_t)v.y * 128 + c0);
      }
      const float yx = lcx * scx + shx, yy = lcy * scy + shy;
      const float uex = yx * sigm(yx), uey = yy * sigm(yy);
      __builtin_nontemporal_store((f32x2){uex, uey}, (f32x2*)(outE + (size_t)ec * 128 + c0));
      const float sgx = sigm(uex), sgy = sigm(uey);
      agx += sgx; agy += sgy;
      tcx += sgx * (float)gc.x; tcy += sgy * (float)gc.y;
    }
    const f32x2 sv = *(const f32x2*)(S + (size_t)n * 128 + c0);
    const float hx = sv.x + tcx / (agx + 1e-6f);
    const float hy = sv.y + tcy / (agy + 1e-6f);
    __builtin_nontemporal_store((f32x2){hx, hy}, (f32x2*)(hvec + (size_t)n * 128 + c0));
    psx += hx; psy += hy;
    pqx += hx * hx; pqy += hy * hy;
  }

  __shared__ float red[1024];
  red[wv * 128 + c0] = psx;
  red[wv * 128 + c0 + 1] = psy;
  red[512 + wv * 128 + c0] = pqx;
  red[512 + wv * 128 + c0 + 1] = pqy;
  __syncthreads();
  if (tid < 128) {
    const float s = red[tid] + red[128 + tid] + red[256 + tid] + red[384 + tid];
    const float q = red[512 + tid] + red[640 + tid] + red[768 + tid] + red[896 + tid];
    unsafeAtomicAdd(&nsum[tid], s);
    unsafeAtomicAdd(&nsq[tid], q);
  }
}

// ---------------------------------------------------------------------------
__global__ __launch_bounds__(256) void node_out_k(
    const float* __restrict__ nf, const float* __restrict__ hvec,
    const float* __restrict__ nsum, const float* __restrict__ nsq,
    const float* __restrict__ ng, const float* __restrict__ nb, float invN,
    float* __restrict__ out, int total) {
  __shared__ float sSc[128], sSh[128];
  if (threadIdx.x < 128) {
    const int c = threadIdx.x;
    const float mean = nsum[c] * invN;
    const float var = nsq[c] * invN - mean * mean;
    const float sc = ng[c] * rsqrtf(var + 1e-5f);
    sSc[c] = sc;
    sSh[c] = nb[c] - mean * sc;
  }
  __syncthreads();
  const int stride = gridDim.x * 256;
  for (int idx = blockIdx.x * 256 + threadIdx.x; idx < total; idx += stride) {
    const int h = idx & 127;
    const float y = __builtin_nontemporal_load(hvec + idx) * sSc[h] + sSh[h];
    const float o = __builtin_nontemporal_load(nf + idx) + y * sigm(y);
    __builtin_nontemporal_store(o, out + idx);
  }
}

// ---------------------------------------------------------------------------
extern "C" void kernel_launch(void* const* d_in, const int* in_sizes, int n_in,
                              void* d_out, int out_size, void* d_ws, size_t ws_size,
                              hipStream_t stream) {
  const int* ei = (const int*)d_in[0];
  const float* nf = (const float*)d_in[1];
  const float* ef = (const float*)d_in[2];
  const float* Wg = (const float*)d_in[3];
  // d_in[4] = bg : cancels exactly under BN mean subtraction — unused
  const float* Ws = (const float*)d_in[5];
  const float* bs = (const float*)d_in[6];
  const float* Wd = (const float*)d_in[7];
  const float* bd = (const float*)d_in[8];
  const float* zg = (const float*)d_in[9];
  const float* zb = (const float*)d_in[10];
  const float* ng = (const float*)d_in[11];
  const float* nb = (const float*)d_in[12];

  const int N = in_sizes[1] / 128;
  const int E = in_sizes[2] / 128;
  const size_t NH = (size_t)N * 128;

  char* p = (char*)d_ws;
  auto alloc = [&](size_t bytes) {
    char* r = p;
    p += (bytes + 255) & ~(size_t)255;
    return r;
  };
  float* S    = (float*)alloc(NH * 4);
  float* hvec = (float*)alloc(NH * 4);
  f16* Ah = (f16*)alloc(NH * 2);
  f16* Bh = (f16*)alloc(NH * 2);
  f16* Dh = (f16*)alloc(NH * 2);
  float* st = (float*)alloc(1024 * 4);  // esum,esq,nsum,nsq (512 used)
  float* esum = st;
  float* esq  = st + 128;
  float* nsum = st + 256;
  float* nsq  = st + 384;
  int* cnt  = (int*)alloc((size_t)N * 4);
  int* off  = (int*)alloc((size_t)(N + 1) * 4);
  int* cur  = (int*)alloc((size_t)N * 4);
  int2* ed  = (int2*)alloc((size_t)E * 8);
  int* ssrc = (int*)alloc((size_t)E * 4);
  f16* linh = (f16*)p;
  const bool CSRORD =
      ((size_t)(p - (char*)d_ws) + (size_t)E * 128 * 2) <= ws_size;

  float* outN = (float*)d_out;
  float* outE = outN + NH;  // f32-lin scratch (fallback path), then final ue

  // zero: stats block + cnt (contiguous span incl. padding)
  hipMemsetAsync(st, 0, (size_t)((char*)cnt + (size_t)N * 4 - (char*)st), stream);

  node_gemm_k<<<(N + 31) / 32, 256, 0, stream>>>(nf, Wg, Ws, bs, Wd, bd, Ah, Bh, S, Dh, N);

  hist_k<<<640, 256, 0, stream>>>(ei, cnt, E);
  scan_k<<<1, 1024, 0, stream>>>(cnt, off, cur, N);
  scatter_k<<<640, 256, 0, stream>>>(ei, ei + E, cur, ed, ssrc, E);

  const int numTiles = (E + 63) / 64;
  const int gblocks = numTiles < 1024 ? numTiles : 1024;
  if (CSRORD) {
    edge_lin_k<true><<<gblocks, 256, 0, stream>>>(ei, ef, Wg, Ah, Bh, ed, ssrc,
                                                  linh, nullptr, esum, esq, E, numTiles);
    node_agg_k<true><<<(N + 3) / 4, 256, 0, stream>>>(
        linh, outE, ed, off, Dh, S, esum, esq, zg, zb, 1.0f / (float)E,
        hvec, nsum, nsq, N);
  } else {
    edge_lin_k<false><<<gblocks, 256, 0, stream>>>(ei, ef, Wg, Ah, Bh, ed, ssrc,
                                                   nullptr, outE, esum, esq, E, numTiles);
    node_agg_k<false><<<(N + 3) / 4, 256, 0, stream>>>(
        nullptr, outE, ed, off, Dh, S, esum, esq, zg, zb, 1.0f / (float)E,
        hvec, nsum, nsq, N);
  }
  node_out_k<<<640, 256, 0, stream>>>(nf, hvec, nsum, nsq, ng, nb, 1.0f / (float)N,
                                      outN, (int)NH);
}